// Round 14
// baseline (332.690 us; speedup 1.0000x reference)
//
#include <hip/hip_runtime.h>
#include <math.h>

// Problem constants (fixed by reference)
#define BB   2
#define TT   4096            // tokens per batch
#define NT   (BB*TT)         // 8192 total rows
#define DD   1024
#define CQ   128             // k_query dim
#define TK   8               // top_k
#define NCH  16              // s-splits (partial top-8 lists per query)

typedef __attribute__((ext_vector_type(8))) short short8b;  // 8 bf16 = 4 VGPR
typedef __attribute__((ext_vector_type(4))) float f32x4;

// strict insert: correct vs lax.top_k ties when candidates ascend in index
__device__ __forceinline__ void topk8_insert_strict(float (&v)[TK], int (&ix)[TK],
                                                    float val, int idx) {
    float cv = val; int ci = idx;
#pragma unroll
    for (int i = 0; i < TK; ++i) {
        bool sw = (cv > v[i]);
        float tv = v[i]; int ti = ix[i];
        v[i]  = sw ? cv : tv;  ix[i] = sw ? ci : ti;
        cv    = sw ? tv : cv;  ci    = sw ? ti : ci;
    }
}

// tie-break-aware insert (for merging lists whose index order is mixed)
__device__ __forceinline__ void topk8_insert(float (&v)[TK], int (&ix)[TK],
                                             float val, int idx) {
    float cv = val; int ci = idx;
#pragma unroll
    for (int i = 0; i < TK; ++i) {
        bool sw = (cv > v[i]) || (cv == v[i] && ci < ix[i]);
        float tv = v[i]; int ti = ix[i];
        v[i]  = sw ? cv : tv;  ix[i] = sw ? ci : ti;
        cv    = sw ? tv : cv;  ci    = sw ? ti : ci;
    }
}

__device__ __forceinline__ unsigned int pack_bf16(float a, float b) {
    unsigned int ua = __float_as_uint(a), ub = __float_as_uint(b);
    return (ua >> 16) | (ub & 0xFFFF0000u);
}

// ---------------------------------------------------------------------------
// K1: q/k projection, LDS-tiled 64x64 (unchanged from R13 — proven).
// ---------------------------------------------------------------------------
__global__ __launch_bounds__(256) void proj_kernel(
    const float* __restrict__ x,
    const float* __restrict__ Wq, const float* __restrict__ bq,
    const float* __restrict__ Wk, const float* __restrict__ bk,
    float* __restrict__ q, float* __restrict__ k)
{
    __shared__ float Xs[128 * 68];   // [d][row], 34.0 KB
    __shared__ float Ws[128 * 68];   // [d][col], 34.0 KB

    const int tid = threadIdx.x;
    const int rg  = tid >> 4;            // 0..15 -> rows rg*4..+3
    const int cg  = tid & 15;            // 0..15 -> cols cg*4..+3
    const int r0b = blockIdx.x * 64;
    const int ccb = blockIdx.y * 64;     // combined col base (uniform)
    const bool isK = ccb >= CQ;
    const float* W    = isK ? Wk : Wq;
    const float* bias = isK ? bk : bq;
    const int c0b = isK ? ccb - CQ : ccb;

    const int sr = tid >> 2;             // x row 0..63
    const int lq = tid & 3;
    const int wd = tid >> 1;             // W d-row 0..127
    const int wh = tid & 1;

    float acc[16];
#pragma unroll
    for (int j = 0; j < 16; ++j) acc[j] = 0.f;

    for (int dc = 0; dc < DD; dc += 128) {
#pragma unroll
        for (int p = 0; p < 8; ++p) {
            int d = lq * 4 + p * 16;
            float4 v = *reinterpret_cast<const float4*>(
                x + (size_t)(r0b + sr) * DD + dc + d);
            Xs[(d + 0) * 68 + sr] = v.x;
            Xs[(d + 1) * 68 + sr] = v.y;
            Xs[(d + 2) * 68 + sr] = v.z;
            Xs[(d + 3) * 68 + sr] = v.w;
        }
#pragma unroll
        for (int p = 0; p < 8; ++p) {
            int c = wh * 32 + p * 4;
            float4 v = *reinterpret_cast<const float4*>(
                W + (size_t)(dc + wd) * CQ + c0b + c);
            *reinterpret_cast<float4*>(&Ws[wd * 68 + c]) = v;
        }
        __syncthreads();

#pragma unroll 4
        for (int dd = 0; dd < 128; ++dd) {
            float4 xv = *reinterpret_cast<const float4*>(&Xs[dd * 68 + rg * 4]);
            float4 wv = *reinterpret_cast<const float4*>(&Ws[dd * 68 + cg * 4]);
            acc[0]  = fmaf(xv.x, wv.x, acc[0]);
            acc[1]  = fmaf(xv.x, wv.y, acc[1]);
            acc[2]  = fmaf(xv.x, wv.z, acc[2]);
            acc[3]  = fmaf(xv.x, wv.w, acc[3]);
            acc[4]  = fmaf(xv.y, wv.x, acc[4]);
            acc[5]  = fmaf(xv.y, wv.y, acc[5]);
            acc[6]  = fmaf(xv.y, wv.z, acc[6]);
            acc[7]  = fmaf(xv.y, wv.w, acc[7]);
            acc[8]  = fmaf(xv.z, wv.x, acc[8]);
            acc[9]  = fmaf(xv.z, wv.y, acc[9]);
            acc[10] = fmaf(xv.z, wv.z, acc[10]);
            acc[11] = fmaf(xv.z, wv.w, acc[11]);
            acc[12] = fmaf(xv.w, wv.x, acc[12]);
            acc[13] = fmaf(xv.w, wv.y, acc[13]);
            acc[14] = fmaf(xv.w, wv.z, acc[14]);
            acc[15] = fmaf(xv.w, wv.w, acc[15]);
        }
        __syncthreads();
    }

    float4 bi = *reinterpret_cast<const float4*>(bias + c0b + cg * 4);
    float* outp = isK ? k : q;
#pragma unroll
    for (int i = 0; i < 4; ++i) {
        float4 o;
        o.x = acc[i * 4 + 0] + bi.x;
        o.y = acc[i * 4 + 1] + bi.y;
        o.z = acc[i * 4 + 2] + bi.z;
        o.w = acc[i * 4 + 3] + bi.w;
        *reinterpret_cast<float4*>(
            outp + (size_t)(r0b + rg * 4 + i) * CQ + c0b + cg * 4) = o;
    }
}

// ---------------------------------------------------------------------------
// K1b: gates = sigmoid(x@Wg + bg)   one wave per row (unchanged)
// ---------------------------------------------------------------------------
__global__ __launch_bounds__(256) void gate_kernel(
    const float* __restrict__ x, const float* __restrict__ Wg,
    const float* __restrict__ bg, float* __restrict__ gout)
{
    int wave = threadIdx.x >> 6, lane = threadIdx.x & 63;
    int row  = blockIdx.x * 4 + wave;
    const float* xr = x + (size_t)row * DD;
    float s = 0.f;
#pragma unroll
    for (int i = 0; i < 4; ++i) {
        int d = (i * 64 + lane) * 4;
        float4 xv = *reinterpret_cast<const float4*>(xr + d);
        float4 wv = *reinterpret_cast<const float4*>(Wg + d);
        s = fmaf(xv.x, wv.x, s); s = fmaf(xv.y, wv.y, s);
        s = fmaf(xv.z, wv.z, s); s = fmaf(xv.w, wv.w, s);
    }
#pragma unroll
    for (int off = 32; off; off >>= 1) s += __shfl_xor(s, off);
    if (lane == 0) gout[row] = 1.f / (1.f + expf(-(s + bg[0])));
}

// ---------------------------------------------------------------------------
// K2: MFMA bf16 candidate generation (unchanged from R8 — proven).
// ---------------------------------------------------------------------------
__global__ __launch_bounds__(256, 4) void simtopk_kernel(
    const float* __restrict__ qmat, const float* __restrict__ kmat,
    const float* __restrict__ gates, const float* __restrict__ am,
    int* __restrict__ pi)
{
    __shared__ unsigned int Qb[64 * 64];   // 16KB: row = 64 u32 (128 bf16)
    __shared__ unsigned int Kb[64 * 64];   // 16KB

    const int tid  = threadIdx.x;
    const int lane = tid & 63;
    const int wv   = tid >> 6;             // wave 0..3
    const int qt   = blockIdx.x;           // 0..127
    const int sp   = blockIdx.y;           // 0..15
    const int t0   = qt * 64;
    const int b    = t0 >> 12;

    const int sr = tid >> 2;               // 0..63
    const int sg0 = tid & 3;

    // ---- stage Qb once ----
    {
        const float* src = qmat + (size_t)(t0 + sr) * CQ;
#pragma unroll
        for (int j = 0; j < 4; ++j) {
            int g = sg0 + j * 4;
            float4 f0 = *reinterpret_cast<const float4*>(src + g * 8);
            float4 f1 = *reinterpret_cast<const float4*>(src + g * 8 + 4);
            uint4 u;
            u.x = pack_bf16(f0.x, f0.y); u.y = pack_bf16(f0.z, f0.w);
            u.z = pack_bf16(f1.x, f1.y); u.w = pack_bf16(f1.z, f1.w);
            *reinterpret_cast<uint4*>(&Qb[sr * 64 + ((g ^ (sr & 7)) << 2)]) = u;
        }
    }
    // ---- stage Kb chunk 0 ----
    {
        const float* src = kmat + (size_t)(b * TT + sp * 256 + sr) * CQ;
#pragma unroll
        for (int j = 0; j < 4; ++j) {
            int g = sg0 + j * 4;
            float4 f0 = *reinterpret_cast<const float4*>(src + g * 8);
            float4 f1 = *reinterpret_cast<const float4*>(src + g * 8 + 4);
            uint4 u;
            u.x = pack_bf16(f0.x, f0.y); u.y = pack_bf16(f0.z, f0.w);
            u.z = pack_bf16(f1.x, f1.y); u.w = pack_bf16(f1.z, f1.w);
            *reinterpret_cast<uint4*>(&Kb[sr * 64 + ((g ^ (sr & 7)) << 2)]) = u;
        }
    }

    const int l15  = lane & 15;
    const int l4   = lane >> 4;            // quarter 0..3
    const int qrow = wv * 16 + l15;        // query within block
    const int tq   = t0 + qrow;

    const float gate = gates[tq];
    const float mq   = am[tq];
    const float sgq  = 0.08838834764831845f * gate;
    const float mneg = -1e9f * gate;

    float tv[TK]; int tix[TK];
#pragma unroll
    for (int j = 0; j < TK; ++j) { tv[j] = -3.0e38f; tix[j] = 0; }

    const int koff = l4 * 4;
    __syncthreads();

    for (int ck = 0; ck < 4; ++ck) {
        f32x4 c0 = {0.f, 0.f, 0.f, 0.f};
        f32x4 c1 = {0.f, 0.f, 0.f, 0.f};
        f32x4 c2 = {0.f, 0.f, 0.f, 0.f};
        f32x4 c3 = {0.f, 0.f, 0.f, 0.f};
#pragma unroll
        for (int kb = 0; kb < 4; ++kb) {
            int gq = (kb * 4 + l4);
            short8b bq = *reinterpret_cast<const short8b*>(
                &Qb[qrow * 64 + (((gq) ^ (qrow & 7)) << 2)]);
            int r0 = l15,      p0 = ((gq) ^ (r0 & 7)) << 2;
            int r1 = 16 + l15, p1 = ((gq) ^ (r1 & 7)) << 2;
            int r2 = 32 + l15, p2 = ((gq) ^ (r2 & 7)) << 2;
            int r3 = 48 + l15, p3 = ((gq) ^ (r3 & 7)) << 2;
            short8b a0 = *reinterpret_cast<const short8b*>(&Kb[r0 * 64 + p0]);
            short8b a1 = *reinterpret_cast<const short8b*>(&Kb[r1 * 64 + p1]);
            short8b a2 = *reinterpret_cast<const short8b*>(&Kb[r2 * 64 + p2]);
            short8b a3 = *reinterpret_cast<const short8b*>(&Kb[r3 * 64 + p3]);
            c0 = __builtin_amdgcn_mfma_f32_16x16x32_bf16(a0, bq, c0, 0, 0, 0);
            c1 = __builtin_amdgcn_mfma_f32_16x16x32_bf16(a1, bq, c1, 0, 0, 0);
            c2 = __builtin_amdgcn_mfma_f32_16x16x32_bf16(a2, bq, c2, 0, 0, 0);
            c3 = __builtin_amdgcn_mfma_f32_16x16x32_bf16(a3, bq, c3, 0, 0, 0);
        }

        float4 pf[8];
        if (ck < 3) {
            const float* src = kmat +
                (size_t)(b * TT + sp * 256 + (ck + 1) * 64 + sr) * CQ;
#pragma unroll
            for (int j = 0; j < 4; ++j) {
                int g = sg0 + j * 4;
                pf[j * 2 + 0] = *reinterpret_cast<const float4*>(src + g * 8);
                pf[j * 2 + 1] = *reinterpret_cast<const float4*>(src + g * 8 + 4);
            }
        }

        {
            const int sB = sp * 256 + ck * 64;
            const float* amB = am + b * TT + sB;
            float val;
#define SCAN_TILE(CC, KT)                                                    \
            {                                                                \
                float4 amv = *reinterpret_cast<const float4*>(               \
                    amB + (KT) * 16 + koff);                                 \
                int kbase = sB + (KT) * 16 + koff;                           \
                val = (mq * amv.x == 0.f) ? mneg : CC.x * sgq;               \
                if (val > tv[TK-1]) topk8_insert_strict(tv, tix, val, kbase);\
                val = (mq * amv.y == 0.f) ? mneg : CC.y * sgq;               \
                if (val > tv[TK-1]) topk8_insert_strict(tv, tix, val, kbase+1);\
                val = (mq * amv.z == 0.f) ? mneg : CC.z * sgq;               \
                if (val > tv[TK-1]) topk8_insert_strict(tv, tix, val, kbase+2);\
                val = (mq * amv.w == 0.f) ? mneg : CC.w * sgq;               \
                if (val > tv[TK-1]) topk8_insert_strict(tv, tix, val, kbase+3);\
            }
            SCAN_TILE(c0, 0)
            SCAN_TILE(c1, 1)
            SCAN_TILE(c2, 2)
            SCAN_TILE(c3, 3)
#undef SCAN_TILE
        }
        __syncthreads();

        if (ck < 3) {
#pragma unroll
            for (int j = 0; j < 4; ++j) {
                int g = sg0 + j * 4;
                uint4 u;
                u.x = pack_bf16(pf[j*2].x, pf[j*2].y);
                u.y = pack_bf16(pf[j*2].z, pf[j*2].w);
                u.z = pack_bf16(pf[j*2+1].x, pf[j*2+1].y);
                u.w = pack_bf16(pf[j*2+1].z, pf[j*2+1].w);
                *reinterpret_cast<uint4*>(&Kb[sr * 64 + ((g ^ (sr & 7)) << 2)]) = u;
            }
        }
        __syncthreads();
    }

    // ---- merge the 4 lane-quarters per query (tie-aware) ----
    float* mv = reinterpret_cast<float*>(Qb);
    int*   mi = reinterpret_cast<int*>(Kb);
    int slot = qrow * 4 + l4;
#pragma unroll
    for (int j = 0; j < TK; ++j) { mv[slot * 9 + j] = tv[j]; mi[slot * 9 + j] = tix[j]; }
    __syncthreads();
    if (l4 == 0) {
        for (int u = 1; u < 4; ++u) {
#pragma unroll
            for (int j = 0; j < TK; ++j) {
                float val = mv[(slot + u) * 9 + j];
                int   s   = mi[(slot + u) * 9 + j];
                if (val > tv[TK-1] || (val == tv[TK-1] && s < tix[TK-1]))
                    topk8_insert(tv, tix, val, s);
            }
        }
        int base = (tq * NCH + sp) * TK;
#pragma unroll
        for (int j = 0; j < TK; ++j) pi[base + j] = tix[j];
    }
}

// ---------------------------------------------------------------------------
// K3a: f64 rescore + all-pairs rank only (gather split off -> K3b).
// Logic identical to R13's K3 minus the gather tail.
// ---------------------------------------------------------------------------
__global__ __launch_bounds__(256) void rank_kernel(
    const float* __restrict__ qm, const float* __restrict__ kmat,
    const float* __restrict__ gates, const float* __restrict__ am,
    const int* __restrict__ pi,
    float* __restrict__ out_i, float* __restrict__ out_v)
{
    int t = blockIdx.x;
    int b = t >> 12;
    int tid = threadIdx.x;

    __shared__ float  qrow[CQ];
    __shared__ double svald[NCH * TK];
    __shared__ int    scand[NCH * TK];

    if (tid < 32) {
        *reinterpret_cast<float4*>(qrow + tid * 4) =
            *reinterpret_cast<const float4*>(qm + (size_t)t * CQ + tid * 4);
    }
    __syncthreads();

    // ---- rescore: c = tid>>1, half = tid&1 handles dims half*64..+63 ----
    {
        int c    = tid >> 1;
        int half = tid & 1;
        int s = pi[(size_t)t * NCH * TK + c];
        const float* kr = kmat + (size_t)(b * TT + s) * CQ + half * 64;
        const float* qh = qrow + half * 64;
        double a0 = 0.0, a1 = 0.0, a2 = 0.0, a3 = 0.0;
#pragma unroll
        for (int d = 0; d < 64; d += 4) {
            float4 kv = *reinterpret_cast<const float4*>(kr + d);
            a0 += (double)qh[d + 0] * (double)kv.x;
            a1 += (double)qh[d + 1] * (double)kv.y;
            a2 += (double)qh[d + 2] * (double)kv.z;
            a3 += (double)qh[d + 3] * (double)kv.w;
        }
        double mine  = (a0 + a1) + (a2 + a3);
        double other = __shfl_xor(mine, 1);
        double lo = half ? other : mine;
        double hi = half ? mine  : other;
        double acc = lo + hi;                       // identical on both lanes
        if (half == 0) {
            float ms  = am[b * TT + s];
            float mqq = am[t];
            double val = (mqq * ms == 0.f) ? -1e9 : acc * 0.08838834764831845;
            val *= (double)gates[t];
            svald[c] = val;
            scand[c] = s;
        }
    }
    __syncthreads();

    // ---- all-pairs rank (parallel top-8; candidates are distinct) ----
    if (tid < NCH * TK) {
        double v = svald[tid]; int si = scand[tid];
        int rank = 0;
        for (int c2 = 0; c2 < NCH * TK; ++c2) {
            double v2 = svald[c2]; int s2 = scand[c2];
            rank += (v2 > v) || (v2 == v && s2 < si);
        }
        if (rank < TK) {
            out_i[t * TK + rank] = (float)si;
            out_v[t * TK + rank] = (float)v;
        }
    }
}

// ---------------------------------------------------------------------------
// K3b: gather. grid (NT, 2); block copies 4 of the 8 selected x-rows.
// Pure streaming copy, no LDS chains, 16384 blocks for TLP latency hiding.
// Row index read from out_i (float-exact for idx < 4096).
// ---------------------------------------------------------------------------
__global__ __launch_bounds__(256) void gather_kernel(
    const float* __restrict__ x, const float* __restrict__ out_i,
    float* __restrict__ out_g)
{
    int t   = blockIdx.x;
    int b   = t >> 12;
    int j0  = blockIdx.y * 4;
    int tid = threadIdx.x;

#pragma unroll
    for (int jj = 0; jj < 4; ++jj) {
        int j   = j0 + jj;
        int row = (int)out_i[t * TK + j];
        f32x4 v = *reinterpret_cast<const f32x4*>(
            x + ((size_t)(b * TT + row)) * DD + tid * 4);
        __builtin_nontemporal_store(v, reinterpret_cast<f32x4*>(
            out_g + ((size_t)(t * TK + j)) * DD + tid * 4));
    }
}

// ---------------------------------------------------------------------------
extern "C" void kernel_launch(void* const* d_in, const int* in_sizes, int n_in,
                              void* d_out, int out_size, void* d_ws, size_t ws_size,
                              hipStream_t stream) {
    const float* x  = (const float*)d_in[0];
    const float* am = (const float*)d_in[1];
    const float* Wq = (const float*)d_in[2];
    const float* bq = (const float*)d_in[3];
    const float* Wk = (const float*)d_in[4];
    const float* bk = (const float*)d_in[5];
    const float* Wg = (const float*)d_in[6];
    const float* bg = (const float*)d_in[7];

    float* ws = (float*)d_ws;
    float* q  = ws;                              // NT*CQ      = 1048576
    float* k  = ws + 1048576;                    // NT*CQ      = 1048576
    float* g  = ws + 2097152;                    // NT         = 8192
    int*   pi = (int*)(ws + 2105344);            // NT*NCH*TK  = 1048576

    float* out_g = (float*)d_out;                // [B,T,K,D] = 67108864
    float* out_i = out_g + 67108864;             // [B,T,K]   = 65536 (as float)
    float* out_v = out_i + 65536;                // [B,T,K]   = 65536

    proj_kernel<<<dim3(NT / 64, 4), 256, 0, stream>>>(x, Wq, bq, Wk, bk, q, k);
    gate_kernel<<<NT / 4, 256, 0, stream>>>(x, Wg, bg, g);
    simtopk_kernel<<<dim3(128, NCH), 256, 0, stream>>>(q, k, g, am, pi);
    rank_kernel<<<NT, 256, 0, stream>>>(q, k, g, am, pi, out_i, out_v);
    gather_kernel<<<dim3(NT, 2), 256, 0, stream>>>(x, out_i, out_g);
}

// Round 15
// 302.907 us; speedup vs baseline: 1.0983x; 1.0983x over previous
//
#include <hip/hip_runtime.h>
#include <math.h>

// Problem constants (fixed by reference)
#define BB   2
#define TT   4096            // tokens per batch
#define NT   (BB*TT)         // 8192 total rows
#define DD   1024
#define CQ   128             // k_query dim
#define TK   8               // top_k
#define NCH  16              // s-splits (partial top-8 lists per query)

typedef __attribute__((ext_vector_type(8))) short short8b;  // 8 bf16 = 4 VGPR
typedef __attribute__((ext_vector_type(4))) float f32x4;

// strict insert: correct vs lax.top_k ties when candidates ascend in index
__device__ __forceinline__ void topk8_insert_strict(float (&v)[TK], int (&ix)[TK],
                                                    float val, int idx) {
    float cv = val; int ci = idx;
#pragma unroll
    for (int i = 0; i < TK; ++i) {
        bool sw = (cv > v[i]);
        float tv = v[i]; int ti = ix[i];
        v[i]  = sw ? cv : tv;  ix[i] = sw ? ci : ti;
        cv    = sw ? tv : cv;  ci    = sw ? ti : ci;
    }
}

// tie-break-aware insert (for merging lists whose index order is mixed)
__device__ __forceinline__ void topk8_insert(float (&v)[TK], int (&ix)[TK],
                                             float val, int idx) {
    float cv = val; int ci = idx;
#pragma unroll
    for (int i = 0; i < TK; ++i) {
        bool sw = (cv > v[i]) || (cv == v[i] && ci < ix[i]);
        float tv = v[i]; int ti = ix[i];
        v[i]  = sw ? cv : tv;  ix[i] = sw ? ci : ti;
        cv    = sw ? tv : cv;  ci    = sw ? ti : ci;
    }
}

__device__ __forceinline__ unsigned int pack_bf16(float a, float b) {
    unsigned int ua = __float_as_uint(a), ub = __float_as_uint(b);
    return (ua >> 16) | (ub & 0xFFFF0000u);
}

// ---------------------------------------------------------------------------
// K1: q = x@Wq + bq ; k = x@Wk + bk.  LDS-tiled 64 rows x 64 combined cols.
// Thread = 4x4 outputs, acc[16] flat scalar (the proven non-spilling shape).
// ---------------------------------------------------------------------------
__global__ __launch_bounds__(256) void proj_kernel(
    const float* __restrict__ x,
    const float* __restrict__ Wq, const float* __restrict__ bq,
    const float* __restrict__ Wk, const float* __restrict__ bk,
    float* __restrict__ q, float* __restrict__ k)
{
    __shared__ float Xs[128 * 68];   // [d][row], 34.0 KB
    __shared__ float Ws[128 * 68];   // [d][col], 34.0 KB

    const int tid = threadIdx.x;
    const int rg  = tid >> 4;            // 0..15 -> rows rg*4..+3
    const int cg  = tid & 15;            // 0..15 -> cols cg*4..+3
    const int r0b = blockIdx.x * 64;
    const int ccb = blockIdx.y * 64;     // combined col base (uniform)
    const bool isK = ccb >= CQ;
    const float* W    = isK ? Wk : Wq;
    const float* bias = isK ? bk : bq;
    const int c0b = isK ? ccb - CQ : ccb;

    const int sr = tid >> 2;             // x row 0..63
    const int lq = tid & 3;
    const int wd = tid >> 1;             // W d-row 0..127
    const int wh = tid & 1;

    float acc[16];
#pragma unroll
    for (int j = 0; j < 16; ++j) acc[j] = 0.f;

    for (int dc = 0; dc < DD; dc += 128) {
#pragma unroll
        for (int p = 0; p < 8; ++p) {
            int d = lq * 4 + p * 16;
            float4 v = *reinterpret_cast<const float4*>(
                x + (size_t)(r0b + sr) * DD + dc + d);
            Xs[(d + 0) * 68 + sr] = v.x;
            Xs[(d + 1) * 68 + sr] = v.y;
            Xs[(d + 2) * 68 + sr] = v.z;
            Xs[(d + 3) * 68 + sr] = v.w;
        }
#pragma unroll
        for (int p = 0; p < 8; ++p) {
            int c = wh * 32 + p * 4;
            float4 v = *reinterpret_cast<const float4*>(
                W + (size_t)(dc + wd) * CQ + c0b + c);
            *reinterpret_cast<float4*>(&Ws[wd * 68 + c]) = v;
        }
        __syncthreads();

#pragma unroll 4
        for (int dd = 0; dd < 128; ++dd) {
            float4 xv = *reinterpret_cast<const float4*>(&Xs[dd * 68 + rg * 4]);
            float4 wv = *reinterpret_cast<const float4*>(&Ws[dd * 68 + cg * 4]);
            acc[0]  = fmaf(xv.x, wv.x, acc[0]);
            acc[1]  = fmaf(xv.x, wv.y, acc[1]);
            acc[2]  = fmaf(xv.x, wv.z, acc[2]);
            acc[3]  = fmaf(xv.x, wv.w, acc[3]);
            acc[4]  = fmaf(xv.y, wv.x, acc[4]);
            acc[5]  = fmaf(xv.y, wv.y, acc[5]);
            acc[6]  = fmaf(xv.y, wv.z, acc[6]);
            acc[7]  = fmaf(xv.y, wv.w, acc[7]);
            acc[8]  = fmaf(xv.z, wv.x, acc[8]);
            acc[9]  = fmaf(xv.z, wv.y, acc[9]);
            acc[10] = fmaf(xv.z, wv.z, acc[10]);
            acc[11] = fmaf(xv.z, wv.w, acc[11]);
            acc[12] = fmaf(xv.w, wv.x, acc[12]);
            acc[13] = fmaf(xv.w, wv.y, acc[13]);
            acc[14] = fmaf(xv.w, wv.z, acc[14]);
            acc[15] = fmaf(xv.w, wv.w, acc[15]);
        }
        __syncthreads();
    }

    float4 bi = *reinterpret_cast<const float4*>(bias + c0b + cg * 4);
    float* outp = isK ? k : q;
#pragma unroll
    for (int i = 0; i < 4; ++i) {
        float4 o;
        o.x = acc[i * 4 + 0] + bi.x;
        o.y = acc[i * 4 + 1] + bi.y;
        o.z = acc[i * 4 + 2] + bi.z;
        o.w = acc[i * 4 + 3] + bi.w;
        *reinterpret_cast<float4*>(
            outp + (size_t)(r0b + rg * 4 + i) * CQ + c0b + cg * 4) = o;
    }
}

// ---------------------------------------------------------------------------
// K1b: gates = sigmoid(x@Wg + bg)   one wave per row (unchanged)
// ---------------------------------------------------------------------------
__global__ __launch_bounds__(256) void gate_kernel(
    const float* __restrict__ x, const float* __restrict__ Wg,
    const float* __restrict__ bg, float* __restrict__ gout)
{
    int wave = threadIdx.x >> 6, lane = threadIdx.x & 63;
    int row  = blockIdx.x * 4 + wave;
    const float* xr = x + (size_t)row * DD;
    float s = 0.f;
#pragma unroll
    for (int i = 0; i < 4; ++i) {
        int d = (i * 64 + lane) * 4;
        float4 xv = *reinterpret_cast<const float4*>(xr + d);
        float4 wv = *reinterpret_cast<const float4*>(Wg + d);
        s = fmaf(xv.x, wv.x, s); s = fmaf(xv.y, wv.y, s);
        s = fmaf(xv.z, wv.z, s); s = fmaf(xv.w, wv.w, s);
    }
#pragma unroll
    for (int off = 32; off; off >>= 1) s += __shfl_xor(s, off);
    if (lane == 0) gout[row] = 1.f / (1.f + expf(-(s + bg[0])));
}

// ---------------------------------------------------------------------------
// K2: MFMA bf16 candidate generation (unchanged from R8 — proven).
// ---------------------------------------------------------------------------
__global__ __launch_bounds__(256, 4) void simtopk_kernel(
    const float* __restrict__ qmat, const float* __restrict__ kmat,
    const float* __restrict__ gates, const float* __restrict__ am,
    int* __restrict__ pi)
{
    __shared__ unsigned int Qb[64 * 64];   // 16KB: row = 64 u32 (128 bf16)
    __shared__ unsigned int Kb[64 * 64];   // 16KB

    const int tid  = threadIdx.x;
    const int lane = tid & 63;
    const int wv   = tid >> 6;             // wave 0..3
    const int qt   = blockIdx.x;           // 0..127
    const int sp   = blockIdx.y;           // 0..15
    const int t0   = qt * 64;
    const int b    = t0 >> 12;

    const int sr = tid >> 2;               // 0..63
    const int sg0 = tid & 3;

    // ---- stage Qb once ----
    {
        const float* src = qmat + (size_t)(t0 + sr) * CQ;
#pragma unroll
        for (int j = 0; j < 4; ++j) {
            int g = sg0 + j * 4;
            float4 f0 = *reinterpret_cast<const float4*>(src + g * 8);
            float4 f1 = *reinterpret_cast<const float4*>(src + g * 8 + 4);
            uint4 u;
            u.x = pack_bf16(f0.x, f0.y); u.y = pack_bf16(f0.z, f0.w);
            u.z = pack_bf16(f1.x, f1.y); u.w = pack_bf16(f1.z, f1.w);
            *reinterpret_cast<uint4*>(&Qb[sr * 64 + ((g ^ (sr & 7)) << 2)]) = u;
        }
    }
    // ---- stage Kb chunk 0 ----
    {
        const float* src = kmat + (size_t)(b * TT + sp * 256 + sr) * CQ;
#pragma unroll
        for (int j = 0; j < 4; ++j) {
            int g = sg0 + j * 4;
            float4 f0 = *reinterpret_cast<const float4*>(src + g * 8);
            float4 f1 = *reinterpret_cast<const float4*>(src + g * 8 + 4);
            uint4 u;
            u.x = pack_bf16(f0.x, f0.y); u.y = pack_bf16(f0.z, f0.w);
            u.z = pack_bf16(f1.x, f1.y); u.w = pack_bf16(f1.z, f1.w);
            *reinterpret_cast<uint4*>(&Kb[sr * 64 + ((g ^ (sr & 7)) << 2)]) = u;
        }
    }

    const int l15  = lane & 15;
    const int l4   = lane >> 4;            // quarter 0..3
    const int qrow = wv * 16 + l15;        // query within block
    const int tq   = t0 + qrow;

    const float gate = gates[tq];
    const float mq   = am[tq];
    const float sgq  = 0.08838834764831845f * gate;
    const float mneg = -1e9f * gate;

    float tv[TK]; int tix[TK];
#pragma unroll
    for (int j = 0; j < TK; ++j) { tv[j] = -3.0e38f; tix[j] = 0; }

    const int koff = l4 * 4;
    __syncthreads();

    for (int ck = 0; ck < 4; ++ck) {
        f32x4 c0 = {0.f, 0.f, 0.f, 0.f};
        f32x4 c1 = {0.f, 0.f, 0.f, 0.f};
        f32x4 c2 = {0.f, 0.f, 0.f, 0.f};
        f32x4 c3 = {0.f, 0.f, 0.f, 0.f};
#pragma unroll
        for (int kb = 0; kb < 4; ++kb) {
            int gq = (kb * 4 + l4);
            short8b bq = *reinterpret_cast<const short8b*>(
                &Qb[qrow * 64 + (((gq) ^ (qrow & 7)) << 2)]);
            int r0 = l15,      p0 = ((gq) ^ (r0 & 7)) << 2;
            int r1 = 16 + l15, p1 = ((gq) ^ (r1 & 7)) << 2;
            int r2 = 32 + l15, p2 = ((gq) ^ (r2 & 7)) << 2;
            int r3 = 48 + l15, p3 = ((gq) ^ (r3 & 7)) << 2;
            short8b a0 = *reinterpret_cast<const short8b*>(&Kb[r0 * 64 + p0]);
            short8b a1 = *reinterpret_cast<const short8b*>(&Kb[r1 * 64 + p1]);
            short8b a2 = *reinterpret_cast<const short8b*>(&Kb[r2 * 64 + p2]);
            short8b a3 = *reinterpret_cast<const short8b*>(&Kb[r3 * 64 + p3]);
            c0 = __builtin_amdgcn_mfma_f32_16x16x32_bf16(a0, bq, c0, 0, 0, 0);
            c1 = __builtin_amdgcn_mfma_f32_16x16x32_bf16(a1, bq, c1, 0, 0, 0);
            c2 = __builtin_amdgcn_mfma_f32_16x16x32_bf16(a2, bq, c2, 0, 0, 0);
            c3 = __builtin_amdgcn_mfma_f32_16x16x32_bf16(a3, bq, c3, 0, 0, 0);
        }

        float4 pf[8];
        if (ck < 3) {
            const float* src = kmat +
                (size_t)(b * TT + sp * 256 + (ck + 1) * 64 + sr) * CQ;
#pragma unroll
            for (int j = 0; j < 4; ++j) {
                int g = sg0 + j * 4;
                pf[j * 2 + 0] = *reinterpret_cast<const float4*>(src + g * 8);
                pf[j * 2 + 1] = *reinterpret_cast<const float4*>(src + g * 8 + 4);
            }
        }

        {
            const int sB = sp * 256 + ck * 64;
            const float* amB = am + b * TT + sB;
            float val;
#define SCAN_TILE(CC, KT)                                                    \
            {                                                                \
                float4 amv = *reinterpret_cast<const float4*>(               \
                    amB + (KT) * 16 + koff);                                 \
                int kbase = sB + (KT) * 16 + koff;                           \
                val = (mq * amv.x == 0.f) ? mneg : CC.x * sgq;               \
                if (val > tv[TK-1]) topk8_insert_strict(tv, tix, val, kbase);\
                val = (mq * amv.y == 0.f) ? mneg : CC.y * sgq;               \
                if (val > tv[TK-1]) topk8_insert_strict(tv, tix, val, kbase+1);\
                val = (mq * amv.z == 0.f) ? mneg : CC.z * sgq;               \
                if (val > tv[TK-1]) topk8_insert_strict(tv, tix, val, kbase+2);\
                val = (mq * amv.w == 0.f) ? mneg : CC.w * sgq;               \
                if (val > tv[TK-1]) topk8_insert_strict(tv, tix, val, kbase+3);\
            }
            SCAN_TILE(c0, 0)
            SCAN_TILE(c1, 1)
            SCAN_TILE(c2, 2)
            SCAN_TILE(c3, 3)
#undef SCAN_TILE
        }
        __syncthreads();

        if (ck < 3) {
#pragma unroll
            for (int j = 0; j < 4; ++j) {
                int g = sg0 + j * 4;
                uint4 u;
                u.x = pack_bf16(pf[j*2].x, pf[j*2].y);
                u.y = pack_bf16(pf[j*2].z, pf[j*2].w);
                u.z = pack_bf16(pf[j*2+1].x, pf[j*2+1].y);
                u.w = pack_bf16(pf[j*2+1].z, pf[j*2+1].w);
                *reinterpret_cast<uint4*>(&Kb[sr * 64 + ((g ^ (sr & 7)) << 2)]) = u;
            }
        }
        __syncthreads();
    }

    // ---- merge the 4 lane-quarters per query (tie-aware) ----
    float* mv = reinterpret_cast<float*>(Qb);
    int*   mi = reinterpret_cast<int*>(Kb);
    int slot = qrow * 4 + l4;
#pragma unroll
    for (int j = 0; j < TK; ++j) { mv[slot * 9 + j] = tv[j]; mi[slot * 9 + j] = tix[j]; }
    __syncthreads();
    if (l4 == 0) {
        for (int u = 1; u < 4; ++u) {
#pragma unroll
            for (int j = 0; j < TK; ++j) {
                float val = mv[(slot + u) * 9 + j];
                int   s   = mi[(slot + u) * 9 + j];
                if (val > tv[TK-1] || (val == tv[TK-1] && s < tix[TK-1]))
                    topk8_insert(tv, tix, val, s);
            }
        }
        int base = (tq * NCH + sp) * TK;
#pragma unroll
        for (int j = 0; j < TK; ++j) pi[base + j] = tix[j];
    }
}

// ---------------------------------------------------------------------------
// K3: fully parallel exact ranking + gather, FUSED (R13 — proven best: the
// gather phase of each block overlaps other blocks' rescore/rank phases;
// splitting into two kernels lost that overlap, +37us in R14).
// ---------------------------------------------------------------------------
__global__ __launch_bounds__(256) void merge_gather_kernel(
    const float* __restrict__ x,  const float* __restrict__ qm,
    const float* __restrict__ kmat, const float* __restrict__ gates,
    const float* __restrict__ am, const int* __restrict__ pi,
    float* __restrict__ out_g, float* __restrict__ out_i,
    float* __restrict__ out_v)
{
    int t = blockIdx.x;
    int b = t >> 12;
    int tid = threadIdx.x;

    __shared__ float  qrow[CQ];
    __shared__ double svald[NCH * TK];
    __shared__ int    scand[NCH * TK];
    __shared__ int    fidx[TK];

    if (tid < 32) {
        *reinterpret_cast<float4*>(qrow + tid * 4) =
            *reinterpret_cast<const float4*>(qm + (size_t)t * CQ + tid * 4);
    }
    __syncthreads();

    // ---- rescore: c = tid>>1, half = tid&1 handles dims half*64..+63 ----
    {
        int c    = tid >> 1;
        int half = tid & 1;
        int s = pi[(size_t)t * NCH * TK + c];
        const float* kr = kmat + (size_t)(b * TT + s) * CQ + half * 64;
        const float* qh = qrow + half * 64;
        double a0 = 0.0, a1 = 0.0, a2 = 0.0, a3 = 0.0;
#pragma unroll
        for (int d = 0; d < 64; d += 4) {
            float4 kv = *reinterpret_cast<const float4*>(kr + d);
            a0 += (double)qh[d + 0] * (double)kv.x;
            a1 += (double)qh[d + 1] * (double)kv.y;
            a2 += (double)qh[d + 2] * (double)kv.z;
            a3 += (double)qh[d + 3] * (double)kv.w;
        }
        double mine  = (a0 + a1) + (a2 + a3);
        double other = __shfl_xor(mine, 1);
        double lo = half ? other : mine;
        double hi = half ? mine  : other;
        double acc = lo + hi;                       // identical on both lanes
        if (half == 0) {
            float ms  = am[b * TT + s];
            float mqq = am[t];
            double val = (mqq * ms == 0.f) ? -1e9 : acc * 0.08838834764831845;
            val *= (double)gates[t];
            svald[c] = val;
            scand[c] = s;
        }
    }
    __syncthreads();

    // ---- all-pairs rank (parallel top-8; candidates are distinct) ----
    if (tid < NCH * TK) {
        double v = svald[tid]; int si = scand[tid];
        int rank = 0;
        for (int c2 = 0; c2 < NCH * TK; ++c2) {
            double v2 = svald[c2]; int s2 = scand[c2];
            rank += (v2 > v) || (v2 == v && s2 < si);
        }
        if (rank < TK) {
            out_i[t * TK + rank] = (float)si;
            out_v[t * TK + rank] = (float)v;
            fidx[rank] = si;
        }
    }
    __syncthreads();

    // ---- gather 8 x-rows (nontemporal stores via ext_vector type) ----
#pragma unroll
    for (int j = 0; j < TK; ++j) {
        int row = fidx[j];
        f32x4 val4 = *reinterpret_cast<const f32x4*>(
            x + ((size_t)(b * TT + row)) * DD + tid * 4);
        __builtin_nontemporal_store(val4, reinterpret_cast<f32x4*>(
            out_g + ((size_t)(t * TK + j)) * DD + tid * 4));
    }
}

// ---------------------------------------------------------------------------
extern "C" void kernel_launch(void* const* d_in, const int* in_sizes, int n_in,
                              void* d_out, int out_size, void* d_ws, size_t ws_size,
                              hipStream_t stream) {
    const float* x  = (const float*)d_in[0];
    const float* am = (const float*)d_in[1];
    const float* Wq = (const float*)d_in[2];
    const float* bq = (const float*)d_in[3];
    const float* Wk = (const float*)d_in[4];
    const float* bk = (const float*)d_in[5];
    const float* Wg = (const float*)d_in[6];
    const float* bg = (const float*)d_in[7];

    float* ws = (float*)d_ws;
    float* q  = ws;                              // NT*CQ      = 1048576
    float* k  = ws + 1048576;                    // NT*CQ      = 1048576
    float* g  = ws + 2097152;                    // NT         = 8192
    int*   pi = (int*)(ws + 2105344);            // NT*NCH*TK  = 1048576

    float* out_g = (float*)d_out;                // [B,T,K,D] = 67108864
    float* out_i = out_g + 67108864;             // [B,T,K]   = 65536 (as float)
    float* out_v = out_i + 65536;                // [B,T,K]   = 65536

    proj_kernel<<<dim3(NT / 64, 4), 256, 0, stream>>>(x, Wq, bq, Wk, bk, q, k);
    gate_kernel<<<NT / 4, 256, 0, stream>>>(x, Wg, bg, g);
    simtopk_kernel<<<dim3(128, NCH), 256, 0, stream>>>(q, k, g, am, pi);
    merge_gather_kernel<<<NT, 256, 0, stream>>>(x, q, k, g, am, pi,
                                                out_g, out_i, out_v);
}

// Round 16
// 295.870 us; speedup vs baseline: 1.1244x; 1.0238x over previous
//
#include <hip/hip_runtime.h>
#include <math.h>

// Problem constants (fixed by reference)
#define BB   2
#define TT   4096            // tokens per batch
#define NT   (BB*TT)         // 8192 total rows
#define DD   1024
#define CQ   128             // k_query dim
#define TK   8               // top_k
#define NCH  16              // s-splits (partial top-8 lists per query)

typedef __attribute__((ext_vector_type(8))) short short8b;  // 8 bf16 = 4 VGPR
typedef __attribute__((ext_vector_type(4))) float f32x4;

// strict insert: correct vs lax.top_k ties when candidates ascend in index
__device__ __forceinline__ void topk8_insert_strict(float (&v)[TK], int (&ix)[TK],
                                                    float val, int idx) {
    float cv = val; int ci = idx;
#pragma unroll
    for (int i = 0; i < TK; ++i) {
        bool sw = (cv > v[i]);
        float tv = v[i]; int ti = ix[i];
        v[i]  = sw ? cv : tv;  ix[i] = sw ? ci : ti;
        cv    = sw ? tv : cv;  ci    = sw ? ti : ci;
    }
}

// tie-break-aware insert (for merging lists whose index order is mixed)
__device__ __forceinline__ void topk8_insert(float (&v)[TK], int (&ix)[TK],
                                             float val, int idx) {
    float cv = val; int ci = idx;
#pragma unroll
    for (int i = 0; i < TK; ++i) {
        bool sw = (cv > v[i]) || (cv == v[i] && ci < ix[i]);
        float tv = v[i]; int ti = ix[i];
        v[i]  = sw ? cv : tv;  ix[i] = sw ? ci : ti;
        cv    = sw ? tv : cv;  ci    = sw ? ti : ci;
    }
}

__device__ __forceinline__ unsigned int pack_bf16(float a, float b) {
    unsigned int ua = __float_as_uint(a), ub = __float_as_uint(b);
    return (ua >> 16) | (ub & 0xFFFF0000u);
}

// ---------------------------------------------------------------------------
// K1: q = x@Wq + bq ; k = x@Wk + bk.  LDS-tiled 64 rows x 64 combined cols.
// Thread = 4x4 outputs, acc[16] flat scalar (the proven non-spilling shape).
// ---------------------------------------------------------------------------
__global__ __launch_bounds__(256) void proj_kernel(
    const float* __restrict__ x,
    const float* __restrict__ Wq, const float* __restrict__ bq,
    const float* __restrict__ Wk, const float* __restrict__ bk,
    float* __restrict__ q, float* __restrict__ k)
{
    __shared__ float Xs[128 * 68];   // [d][row], 34.0 KB
    __shared__ float Ws[128 * 68];   // [d][col], 34.0 KB

    const int tid = threadIdx.x;
    const int rg  = tid >> 4;            // 0..15 -> rows rg*4..+3
    const int cg  = tid & 15;            // 0..15 -> cols cg*4..+3
    const int r0b = blockIdx.x * 64;
    const int ccb = blockIdx.y * 64;     // combined col base (uniform)
    const bool isK = ccb >= CQ;
    const float* W    = isK ? Wk : Wq;
    const float* bias = isK ? bk : bq;
    const int c0b = isK ? ccb - CQ : ccb;

    const int sr = tid >> 2;             // x row 0..63
    const int lq = tid & 3;
    const int wd = tid >> 1;             // W d-row 0..127
    const int wh = tid & 1;

    float acc[16];
#pragma unroll
    for (int j = 0; j < 16; ++j) acc[j] = 0.f;

    for (int dc = 0; dc < DD; dc += 128) {
#pragma unroll
        for (int p = 0; p < 8; ++p) {
            int d = lq * 4 + p * 16;
            float4 v = *reinterpret_cast<const float4*>(
                x + (size_t)(r0b + sr) * DD + dc + d);
            Xs[(d + 0) * 68 + sr] = v.x;
            Xs[(d + 1) * 68 + sr] = v.y;
            Xs[(d + 2) * 68 + sr] = v.z;
            Xs[(d + 3) * 68 + sr] = v.w;
        }
#pragma unroll
        for (int p = 0; p < 8; ++p) {
            int c = wh * 32 + p * 4;
            float4 v = *reinterpret_cast<const float4*>(
                W + (size_t)(dc + wd) * CQ + c0b + c);
            *reinterpret_cast<float4*>(&Ws[wd * 68 + c]) = v;
        }
        __syncthreads();

#pragma unroll 4
        for (int dd = 0; dd < 128; ++dd) {
            float4 xv = *reinterpret_cast<const float4*>(&Xs[dd * 68 + rg * 4]);
            float4 wv = *reinterpret_cast<const float4*>(&Ws[dd * 68 + cg * 4]);
            acc[0]  = fmaf(xv.x, wv.x, acc[0]);
            acc[1]  = fmaf(xv.x, wv.y, acc[1]);
            acc[2]  = fmaf(xv.x, wv.z, acc[2]);
            acc[3]  = fmaf(xv.x, wv.w, acc[3]);
            acc[4]  = fmaf(xv.y, wv.x, acc[4]);
            acc[5]  = fmaf(xv.y, wv.y, acc[5]);
            acc[6]  = fmaf(xv.y, wv.z, acc[6]);
            acc[7]  = fmaf(xv.y, wv.w, acc[7]);
            acc[8]  = fmaf(xv.z, wv.x, acc[8]);
            acc[9]  = fmaf(xv.z, wv.y, acc[9]);
            acc[10] = fmaf(xv.z, wv.z, acc[10]);
            acc[11] = fmaf(xv.z, wv.w, acc[11]);
            acc[12] = fmaf(xv.w, wv.x, acc[12]);
            acc[13] = fmaf(xv.w, wv.y, acc[13]);
            acc[14] = fmaf(xv.w, wv.z, acc[14]);
            acc[15] = fmaf(xv.w, wv.w, acc[15]);
        }
        __syncthreads();
    }

    float4 bi = *reinterpret_cast<const float4*>(bias + c0b + cg * 4);
    float* outp = isK ? k : q;
#pragma unroll
    for (int i = 0; i < 4; ++i) {
        float4 o;
        o.x = acc[i * 4 + 0] + bi.x;
        o.y = acc[i * 4 + 1] + bi.y;
        o.z = acc[i * 4 + 2] + bi.z;
        o.w = acc[i * 4 + 3] + bi.w;
        *reinterpret_cast<float4*>(
            outp + (size_t)(r0b + rg * 4 + i) * CQ + c0b + cg * 4) = o;
    }
}

// ---------------------------------------------------------------------------
// K1b: gates = sigmoid(x@Wg + bg)   one wave per row (unchanged)
// ---------------------------------------------------------------------------
__global__ __launch_bounds__(256) void gate_kernel(
    const float* __restrict__ x, const float* __restrict__ Wg,
    const float* __restrict__ bg, float* __restrict__ gout)
{
    int wave = threadIdx.x >> 6, lane = threadIdx.x & 63;
    int row  = blockIdx.x * 4 + wave;
    const float* xr = x + (size_t)row * DD;
    float s = 0.f;
#pragma unroll
    for (int i = 0; i < 4; ++i) {
        int d = (i * 64 + lane) * 4;
        float4 xv = *reinterpret_cast<const float4*>(xr + d);
        float4 wv = *reinterpret_cast<const float4*>(Wg + d);
        s = fmaf(xv.x, wv.x, s); s = fmaf(xv.y, wv.y, s);
        s = fmaf(xv.z, wv.z, s); s = fmaf(xv.w, wv.w, s);
    }
#pragma unroll
    for (int off = 32; off; off >>= 1) s += __shfl_xor(s, off);
    if (lane == 0) gout[row] = 1.f / (1.f + expf(-(s + bg[0])));
}

// ---------------------------------------------------------------------------
// K2: MFMA bf16 candidate generation (unchanged from R8 — proven).
// ---------------------------------------------------------------------------
__global__ __launch_bounds__(256, 4) void simtopk_kernel(
    const float* __restrict__ qmat, const float* __restrict__ kmat,
    const float* __restrict__ gates, const float* __restrict__ am,
    int* __restrict__ pi)
{
    __shared__ unsigned int Qb[64 * 64];   // 16KB: row = 64 u32 (128 bf16)
    __shared__ unsigned int Kb[64 * 64];   // 16KB

    const int tid  = threadIdx.x;
    const int lane = tid & 63;
    const int wv   = tid >> 6;             // wave 0..3
    const int qt   = blockIdx.x;           // 0..127
    const int sp   = blockIdx.y;           // 0..15
    const int t0   = qt * 64;
    const int b    = t0 >> 12;

    const int sr = tid >> 2;               // 0..63
    const int sg0 = tid & 3;

    // ---- stage Qb once ----
    {
        const float* src = qmat + (size_t)(t0 + sr) * CQ;
#pragma unroll
        for (int j = 0; j < 4; ++j) {
            int g = sg0 + j * 4;
            float4 f0 = *reinterpret_cast<const float4*>(src + g * 8);
            float4 f1 = *reinterpret_cast<const float4*>(src + g * 8 + 4);
            uint4 u;
            u.x = pack_bf16(f0.x, f0.y); u.y = pack_bf16(f0.z, f0.w);
            u.z = pack_bf16(f1.x, f1.y); u.w = pack_bf16(f1.z, f1.w);
            *reinterpret_cast<uint4*>(&Qb[sr * 64 + ((g ^ (sr & 7)) << 2)]) = u;
        }
    }
    // ---- stage Kb chunk 0 ----
    {
        const float* src = kmat + (size_t)(b * TT + sp * 256 + sr) * CQ;
#pragma unroll
        for (int j = 0; j < 4; ++j) {
            int g = sg0 + j * 4;
            float4 f0 = *reinterpret_cast<const float4*>(src + g * 8);
            float4 f1 = *reinterpret_cast<const float4*>(src + g * 8 + 4);
            uint4 u;
            u.x = pack_bf16(f0.x, f0.y); u.y = pack_bf16(f0.z, f0.w);
            u.z = pack_bf16(f1.x, f1.y); u.w = pack_bf16(f1.z, f1.w);
            *reinterpret_cast<uint4*>(&Kb[sr * 64 + ((g ^ (sr & 7)) << 2)]) = u;
        }
    }

    const int l15  = lane & 15;
    const int l4   = lane >> 4;            // quarter 0..3
    const int qrow = wv * 16 + l15;        // query within block
    const int tq   = t0 + qrow;

    const float gate = gates[tq];
    const float mq   = am[tq];
    const float sgq  = 0.08838834764831845f * gate;
    const float mneg = -1e9f * gate;

    float tv[TK]; int tix[TK];
#pragma unroll
    for (int j = 0; j < TK; ++j) { tv[j] = -3.0e38f; tix[j] = 0; }

    const int koff = l4 * 4;
    __syncthreads();

    for (int ck = 0; ck < 4; ++ck) {
        f32x4 c0 = {0.f, 0.f, 0.f, 0.f};
        f32x4 c1 = {0.f, 0.f, 0.f, 0.f};
        f32x4 c2 = {0.f, 0.f, 0.f, 0.f};
        f32x4 c3 = {0.f, 0.f, 0.f, 0.f};
#pragma unroll
        for (int kb = 0; kb < 4; ++kb) {
            int gq = (kb * 4 + l4);
            short8b bq = *reinterpret_cast<const short8b*>(
                &Qb[qrow * 64 + (((gq) ^ (qrow & 7)) << 2)]);
            int r0 = l15,      p0 = ((gq) ^ (r0 & 7)) << 2;
            int r1 = 16 + l15, p1 = ((gq) ^ (r1 & 7)) << 2;
            int r2 = 32 + l15, p2 = ((gq) ^ (r2 & 7)) << 2;
            int r3 = 48 + l15, p3 = ((gq) ^ (r3 & 7)) << 2;
            short8b a0 = *reinterpret_cast<const short8b*>(&Kb[r0 * 64 + p0]);
            short8b a1 = *reinterpret_cast<const short8b*>(&Kb[r1 * 64 + p1]);
            short8b a2 = *reinterpret_cast<const short8b*>(&Kb[r2 * 64 + p2]);
            short8b a3 = *reinterpret_cast<const short8b*>(&Kb[r3 * 64 + p3]);
            c0 = __builtin_amdgcn_mfma_f32_16x16x32_bf16(a0, bq, c0, 0, 0, 0);
            c1 = __builtin_amdgcn_mfma_f32_16x16x32_bf16(a1, bq, c1, 0, 0, 0);
            c2 = __builtin_amdgcn_mfma_f32_16x16x32_bf16(a2, bq, c2, 0, 0, 0);
            c3 = __builtin_amdgcn_mfma_f32_16x16x32_bf16(a3, bq, c3, 0, 0, 0);
        }

        float4 pf[8];
        if (ck < 3) {
            const float* src = kmat +
                (size_t)(b * TT + sp * 256 + (ck + 1) * 64 + sr) * CQ;
#pragma unroll
            for (int j = 0; j < 4; ++j) {
                int g = sg0 + j * 4;
                pf[j * 2 + 0] = *reinterpret_cast<const float4*>(src + g * 8);
                pf[j * 2 + 1] = *reinterpret_cast<const float4*>(src + g * 8 + 4);
            }
        }

        {
            const int sB = sp * 256 + ck * 64;
            const float* amB = am + b * TT + sB;
            float val;
#define SCAN_TILE(CC, KT)                                                    \
            {                                                                \
                float4 amv = *reinterpret_cast<const float4*>(               \
                    amB + (KT) * 16 + koff);                                 \
                int kbase = sB + (KT) * 16 + koff;                           \
                val = (mq * amv.x == 0.f) ? mneg : CC.x * sgq;               \
                if (val > tv[TK-1]) topk8_insert_strict(tv, tix, val, kbase);\
                val = (mq * amv.y == 0.f) ? mneg : CC.y * sgq;               \
                if (val > tv[TK-1]) topk8_insert_strict(tv, tix, val, kbase+1);\
                val = (mq * amv.z == 0.f) ? mneg : CC.z * sgq;               \
                if (val > tv[TK-1]) topk8_insert_strict(tv, tix, val, kbase+2);\
                val = (mq * amv.w == 0.f) ? mneg : CC.w * sgq;               \
                if (val > tv[TK-1]) topk8_insert_strict(tv, tix, val, kbase+3);\
            }
            SCAN_TILE(c0, 0)
            SCAN_TILE(c1, 1)
            SCAN_TILE(c2, 2)
            SCAN_TILE(c3, 3)
#undef SCAN_TILE
        }
        __syncthreads();

        if (ck < 3) {
#pragma unroll
            for (int j = 0; j < 4; ++j) {
                int g = sg0 + j * 4;
                uint4 u;
                u.x = pack_bf16(pf[j*2].x, pf[j*2].y);
                u.y = pack_bf16(pf[j*2].z, pf[j*2].w);
                u.z = pack_bf16(pf[j*2+1].x, pf[j*2+1].y);
                u.w = pack_bf16(pf[j*2+1].z, pf[j*2+1].w);
                *reinterpret_cast<uint4*>(&Kb[sr * 64 + ((g ^ (sr & 7)) << 2)]) = u;
            }
        }
        __syncthreads();
    }

    // ---- merge the 4 lane-quarters per query (tie-aware) ----
    float* mv = reinterpret_cast<float*>(Qb);
    int*   mi = reinterpret_cast<int*>(Kb);
    int slot = qrow * 4 + l4;
#pragma unroll
    for (int j = 0; j < TK; ++j) { mv[slot * 9 + j] = tv[j]; mi[slot * 9 + j] = tix[j]; }
    __syncthreads();
    if (l4 == 0) {
        for (int u = 1; u < 4; ++u) {
#pragma unroll
            for (int j = 0; j < TK; ++j) {
                float val = mv[(slot + u) * 9 + j];
                int   s   = mi[(slot + u) * 9 + j];
                if (val > tv[TK-1] || (val == tv[TK-1] && s < tix[TK-1]))
                    topk8_insert(tv, tix, val, s);
            }
        }
        int base = (tq * NCH + sp) * TK;
#pragma unroll
        for (int j = 0; j < TK; ++j) pi[base + j] = tix[j];
    }
}

// ---------------------------------------------------------------------------
// K3: fully parallel exact ranking + gather, FUSED (R13 structure). Change
// vs R15: gather tail batched into {read 8 ids} -> {8 loads, static-index
// register array} -> {8 nontemporal stores} so all 8 16B loads are in flight
// under one vmcnt wait (R15's VGPR_Count=36 proves they were serialized).
// ---------------------------------------------------------------------------
__global__ __launch_bounds__(256) void merge_gather_kernel(
    const float* __restrict__ x,  const float* __restrict__ qm,
    const float* __restrict__ kmat, const float* __restrict__ gates,
    const float* __restrict__ am, const int* __restrict__ pi,
    float* __restrict__ out_g, float* __restrict__ out_i,
    float* __restrict__ out_v)
{
    int t = blockIdx.x;
    int b = t >> 12;
    int tid = threadIdx.x;

    __shared__ float  qrow[CQ];
    __shared__ double svald[NCH * TK];
    __shared__ int    scand[NCH * TK];
    __shared__ int    fidx[TK];

    if (tid < 32) {
        *reinterpret_cast<float4*>(qrow + tid * 4) =
            *reinterpret_cast<const float4*>(qm + (size_t)t * CQ + tid * 4);
    }
    __syncthreads();

    // ---- rescore: c = tid>>1, half = tid&1 handles dims half*64..+63 ----
    {
        int c    = tid >> 1;
        int half = tid & 1;
        int s = pi[(size_t)t * NCH * TK + c];
        const float* kr = kmat + (size_t)(b * TT + s) * CQ + half * 64;
        const float* qh = qrow + half * 64;
        double a0 = 0.0, a1 = 0.0, a2 = 0.0, a3 = 0.0;
#pragma unroll
        for (int d = 0; d < 64; d += 4) {
            float4 kv = *reinterpret_cast<const float4*>(kr + d);
            a0 += (double)qh[d + 0] * (double)kv.x;
            a1 += (double)qh[d + 1] * (double)kv.y;
            a2 += (double)qh[d + 2] * (double)kv.z;
            a3 += (double)qh[d + 3] * (double)kv.w;
        }
        double mine  = (a0 + a1) + (a2 + a3);
        double other = __shfl_xor(mine, 1);
        double lo = half ? other : mine;
        double hi = half ? mine  : other;
        double acc = lo + hi;                       // identical on both lanes
        if (half == 0) {
            float ms  = am[b * TT + s];
            float mqq = am[t];
            double val = (mqq * ms == 0.f) ? -1e9 : acc * 0.08838834764831845;
            val *= (double)gates[t];
            svald[c] = val;
            scand[c] = s;
        }
    }
    __syncthreads();

    // ---- all-pairs rank (parallel top-8; candidates are distinct) ----
    if (tid < NCH * TK) {
        double v = svald[tid]; int si = scand[tid];
        int rank = 0;
        for (int c2 = 0; c2 < NCH * TK; ++c2) {
            double v2 = svald[c2]; int s2 = scand[c2];
            rank += (v2 > v) || (v2 == v && s2 < si);
        }
        if (rank < TK) {
            out_i[t * TK + rank] = (float)si;
            out_v[t * TK + rank] = (float)v;
            fidx[rank] = si;
        }
    }
    __syncthreads();

    // ---- gather: batched loads (all 8 in flight), then batched stores ----
    {
        int rows[TK];
#pragma unroll
        for (int j = 0; j < TK; ++j) rows[j] = fidx[j];

        f32x4 v0 = *reinterpret_cast<const f32x4*>(
            x + ((size_t)(b * TT + rows[0])) * DD + tid * 4);
        f32x4 v1 = *reinterpret_cast<const f32x4*>(
            x + ((size_t)(b * TT + rows[1])) * DD + tid * 4);
        f32x4 v2 = *reinterpret_cast<const f32x4*>(
            x + ((size_t)(b * TT + rows[2])) * DD + tid * 4);
        f32x4 v3 = *reinterpret_cast<const f32x4*>(
            x + ((size_t)(b * TT + rows[3])) * DD + tid * 4);
        f32x4 v4 = *reinterpret_cast<const f32x4*>(
            x + ((size_t)(b * TT + rows[4])) * DD + tid * 4);
        f32x4 v5 = *reinterpret_cast<const f32x4*>(
            x + ((size_t)(b * TT + rows[5])) * DD + tid * 4);
        f32x4 v6 = *reinterpret_cast<const f32x4*>(
            x + ((size_t)(b * TT + rows[6])) * DD + tid * 4);
        f32x4 v7 = *reinterpret_cast<const f32x4*>(
            x + ((size_t)(b * TT + rows[7])) * DD + tid * 4);

        float* og = out_g + (size_t)t * TK * DD + tid * 4;
        __builtin_nontemporal_store(v0, reinterpret_cast<f32x4*>(og + 0 * DD));
        __builtin_nontemporal_store(v1, reinterpret_cast<f32x4*>(og + 1 * DD));
        __builtin_nontemporal_store(v2, reinterpret_cast<f32x4*>(og + 2 * DD));
        __builtin_nontemporal_store(v3, reinterpret_cast<f32x4*>(og + 3 * DD));
        __builtin_nontemporal_store(v4, reinterpret_cast<f32x4*>(og + 4 * DD));
        __builtin_nontemporal_store(v5, reinterpret_cast<f32x4*>(og + 5 * DD));
        __builtin_nontemporal_store(v6, reinterpret_cast<f32x4*>(og + 6 * DD));
        __builtin_nontemporal_store(v7, reinterpret_cast<f32x4*>(og + 7 * DD));
    }
}

// ---------------------------------------------------------------------------
extern "C" void kernel_launch(void* const* d_in, const int* in_sizes, int n_in,
                              void* d_out, int out_size, void* d_ws, size_t ws_size,
                              hipStream_t stream) {
    const float* x  = (const float*)d_in[0];
    const float* am = (const float*)d_in[1];
    const float* Wq = (const float*)d_in[2];
    const float* bq = (const float*)d_in[3];
    const float* Wk = (const float*)d_in[4];
    const float* bk = (const float*)d_in[5];
    const float* Wg = (const float*)d_in[6];
    const float* bg = (const float*)d_in[7];

    float* ws = (float*)d_ws;
    float* q  = ws;                              // NT*CQ      = 1048576
    float* k  = ws + 1048576;                    // NT*CQ      = 1048576
    float* g  = ws + 2097152;                    // NT         = 8192
    int*   pi = (int*)(ws + 2105344);            // NT*NCH*TK  = 1048576

    float* out_g = (float*)d_out;                // [B,T,K,D] = 67108864
    float* out_i = out_g + 67108864;             // [B,T,K]   = 65536 (as float)
    float* out_v = out_i + 65536;                // [B,T,K]   = 65536

    proj_kernel<<<dim3(NT / 64, 4), 256, 0, stream>>>(x, Wq, bq, Wk, bk, q, k);
    gate_kernel<<<NT / 4, 256, 0, stream>>>(x, Wg, bg, g);
    simtopk_kernel<<<dim3(128, NCH), 256, 0, stream>>>(q, k, g, am, pi);
    merge_gather_kernel<<<NT, 256, 0, stream>>>(x, q, k, g, am, pi,
                                                out_g, out_i, out_v);
}

// Round 17
// 294.651 us; speedup vs baseline: 1.1291x; 1.0041x over previous
//
#include <hip/hip_runtime.h>
#include <math.h>

// Problem constants (fixed by reference)
#define BB   2
#define TT   4096            // tokens per batch
#define NT   (BB*TT)         // 8192 total rows
#define DD   1024
#define CQ   128             // k_query dim
#define TK   8               // top_k
#define NCH  16              // s-splits (partial top-8 lists per query)

typedef __attribute__((ext_vector_type(8))) short short8b;  // 8 bf16 = 4 VGPR
typedef __attribute__((ext_vector_type(4))) float f32x4;

// strict insert: correct vs lax.top_k ties when candidates ascend in index
__device__ __forceinline__ void topk8_insert_strict(float (&v)[TK], int (&ix)[TK],
                                                    float val, int idx) {
    float cv = val; int ci = idx;
#pragma unroll
    for (int i = 0; i < TK; ++i) {
        bool sw = (cv > v[i]);
        float tv = v[i]; int ti = ix[i];
        v[i]  = sw ? cv : tv;  ix[i] = sw ? ci : ti;
        cv    = sw ? tv : cv;  ci    = sw ? ti : ci;
    }
}

// tie-break-aware insert (for merging lists whose index order is mixed)
__device__ __forceinline__ void topk8_insert(float (&v)[TK], int (&ix)[TK],
                                             float val, int idx) {
    float cv = val; int ci = idx;
#pragma unroll
    for (int i = 0; i < TK; ++i) {
        bool sw = (cv > v[i]) || (cv == v[i] && ci < ix[i]);
        float tv = v[i]; int ti = ix[i];
        v[i]  = sw ? cv : tv;  ix[i] = sw ? ci : ti;
        cv    = sw ? tv : cv;  ci    = sw ? ti : ci;
    }
}

__device__ __forceinline__ unsigned int pack_bf16(float a, float b) {
    unsigned int ua = __float_as_uint(a), ub = __float_as_uint(b);
    return (ua >> 16) | (ub & 0xFFFF0000u);
}

// ---------------------------------------------------------------------------
// K1: q = x@Wq + bq ; k = x@Wk + bk.  LDS-tiled 64 rows x 64 combined cols.
// Thread = 4x4 outputs, acc[16] flat scalar (the proven non-spilling shape).
// ---------------------------------------------------------------------------
__global__ __launch_bounds__(256) void proj_kernel(
    const float* __restrict__ x,
    const float* __restrict__ Wq, const float* __restrict__ bq,
    const float* __restrict__ Wk, const float* __restrict__ bk,
    float* __restrict__ q, float* __restrict__ k)
{
    __shared__ float Xs[128 * 68];   // [d][row], 34.0 KB
    __shared__ float Ws[128 * 68];   // [d][col], 34.0 KB

    const int tid = threadIdx.x;
    const int rg  = tid >> 4;            // 0..15 -> rows rg*4..+3
    const int cg  = tid & 15;            // 0..15 -> cols cg*4..+3
    const int r0b = blockIdx.x * 64;
    const int ccb = blockIdx.y * 64;     // combined col base (uniform)
    const bool isK = ccb >= CQ;
    const float* W    = isK ? Wk : Wq;
    const float* bias = isK ? bk : bq;
    const int c0b = isK ? ccb - CQ : ccb;

    const int sr = tid >> 2;             // x row 0..63
    const int lq = tid & 3;
    const int wd = tid >> 1;             // W d-row 0..127
    const int wh = tid & 1;

    float acc[16];
#pragma unroll
    for (int j = 0; j < 16; ++j) acc[j] = 0.f;

    for (int dc = 0; dc < DD; dc += 128) {
#pragma unroll
        for (int p = 0; p < 8; ++p) {
            int d = lq * 4 + p * 16;
            float4 v = *reinterpret_cast<const float4*>(
                x + (size_t)(r0b + sr) * DD + dc + d);
            Xs[(d + 0) * 68 + sr] = v.x;
            Xs[(d + 1) * 68 + sr] = v.y;
            Xs[(d + 2) * 68 + sr] = v.z;
            Xs[(d + 3) * 68 + sr] = v.w;
        }
#pragma unroll
        for (int p = 0; p < 8; ++p) {
            int c = wh * 32 + p * 4;
            float4 v = *reinterpret_cast<const float4*>(
                W + (size_t)(dc + wd) * CQ + c0b + c);
            *reinterpret_cast<float4*>(&Ws[wd * 68 + c]) = v;
        }
        __syncthreads();

#pragma unroll 4
        for (int dd = 0; dd < 128; ++dd) {
            float4 xv = *reinterpret_cast<const float4*>(&Xs[dd * 68 + rg * 4]);
            float4 wv = *reinterpret_cast<const float4*>(&Ws[dd * 68 + cg * 4]);
            acc[0]  = fmaf(xv.x, wv.x, acc[0]);
            acc[1]  = fmaf(xv.x, wv.y, acc[1]);
            acc[2]  = fmaf(xv.x, wv.z, acc[2]);
            acc[3]  = fmaf(xv.x, wv.w, acc[3]);
            acc[4]  = fmaf(xv.y, wv.x, acc[4]);
            acc[5]  = fmaf(xv.y, wv.y, acc[5]);
            acc[6]  = fmaf(xv.y, wv.z, acc[6]);
            acc[7]  = fmaf(xv.y, wv.w, acc[7]);
            acc[8]  = fmaf(xv.z, wv.x, acc[8]);
            acc[9]  = fmaf(xv.z, wv.y, acc[9]);
            acc[10] = fmaf(xv.z, wv.z, acc[10]);
            acc[11] = fmaf(xv.z, wv.w, acc[11]);
            acc[12] = fmaf(xv.w, wv.x, acc[12]);
            acc[13] = fmaf(xv.w, wv.y, acc[13]);
            acc[14] = fmaf(xv.w, wv.z, acc[14]);
            acc[15] = fmaf(xv.w, wv.w, acc[15]);
        }
        __syncthreads();
    }

    float4 bi = *reinterpret_cast<const float4*>(bias + c0b + cg * 4);
    float* outp = isK ? k : q;
#pragma unroll
    for (int i = 0; i < 4; ++i) {
        float4 o;
        o.x = acc[i * 4 + 0] + bi.x;
        o.y = acc[i * 4 + 1] + bi.y;
        o.z = acc[i * 4 + 2] + bi.z;
        o.w = acc[i * 4 + 3] + bi.w;
        *reinterpret_cast<float4*>(
            outp + (size_t)(r0b + rg * 4 + i) * CQ + c0b + cg * 4) = o;
    }
}

// ---------------------------------------------------------------------------
// K1b: gates = sigmoid(x@Wg + bg)   one wave per row (unchanged)
// ---------------------------------------------------------------------------
__global__ __launch_bounds__(256) void gate_kernel(
    const float* __restrict__ x, const float* __restrict__ Wg,
    const float* __restrict__ bg, float* __restrict__ gout)
{
    int wave = threadIdx.x >> 6, lane = threadIdx.x & 63;
    int row  = blockIdx.x * 4 + wave;
    const float* xr = x + (size_t)row * DD;
    float s = 0.f;
#pragma unroll
    for (int i = 0; i < 4; ++i) {
        int d = (i * 64 + lane) * 4;
        float4 xv = *reinterpret_cast<const float4*>(xr + d);
        float4 wv = *reinterpret_cast<const float4*>(Wg + d);
        s = fmaf(xv.x, wv.x, s); s = fmaf(xv.y, wv.y, s);
        s = fmaf(xv.z, wv.z, s); s = fmaf(xv.w, wv.w, s);
    }
#pragma unroll
    for (int off = 32; off; off >>= 1) s += __shfl_xor(s, off);
    if (lane == 0) gout[row] = 1.f / (1.f + expf(-(s + bg[0])));
}

// ---------------------------------------------------------------------------
// K2: MFMA bf16 candidate generation (unchanged from R8 — proven).
// ---------------------------------------------------------------------------
__global__ __launch_bounds__(256, 4) void simtopk_kernel(
    const float* __restrict__ qmat, const float* __restrict__ kmat,
    const float* __restrict__ gates, const float* __restrict__ am,
    int* __restrict__ pi)
{
    __shared__ unsigned int Qb[64 * 64];   // 16KB: row = 64 u32 (128 bf16)
    __shared__ unsigned int Kb[64 * 64];   // 16KB

    const int tid  = threadIdx.x;
    const int lane = tid & 63;
    const int wv   = tid >> 6;             // wave 0..3
    const int qt   = blockIdx.x;           // 0..127
    const int sp   = blockIdx.y;           // 0..15
    const int t0   = qt * 64;
    const int b    = t0 >> 12;

    const int sr = tid >> 2;               // 0..63
    const int sg0 = tid & 3;

    // ---- stage Qb once ----
    {
        const float* src = qmat + (size_t)(t0 + sr) * CQ;
#pragma unroll
        for (int j = 0; j < 4; ++j) {
            int g = sg0 + j * 4;
            float4 f0 = *reinterpret_cast<const float4*>(src + g * 8);
            float4 f1 = *reinterpret_cast<const float4*>(src + g * 8 + 4);
            uint4 u;
            u.x = pack_bf16(f0.x, f0.y); u.y = pack_bf16(f0.z, f0.w);
            u.z = pack_bf16(f1.x, f1.y); u.w = pack_bf16(f1.z, f1.w);
            *reinterpret_cast<uint4*>(&Qb[sr * 64 + ((g ^ (sr & 7)) << 2)]) = u;
        }
    }
    // ---- stage Kb chunk 0 ----
    {
        const float* src = kmat + (size_t)(b * TT + sp * 256 + sr) * CQ;
#pragma unroll
        for (int j = 0; j < 4; ++j) {
            int g = sg0 + j * 4;
            float4 f0 = *reinterpret_cast<const float4*>(src + g * 8);
            float4 f1 = *reinterpret_cast<const float4*>(src + g * 8 + 4);
            uint4 u;
            u.x = pack_bf16(f0.x, f0.y); u.y = pack_bf16(f0.z, f0.w);
            u.z = pack_bf16(f1.x, f1.y); u.w = pack_bf16(f1.z, f1.w);
            *reinterpret_cast<uint4*>(&Kb[sr * 64 + ((g ^ (sr & 7)) << 2)]) = u;
        }
    }

    const int l15  = lane & 15;
    const int l4   = lane >> 4;            // quarter 0..3
    const int qrow = wv * 16 + l15;        // query within block
    const int tq   = t0 + qrow;

    const float gate = gates[tq];
    const float mq   = am[tq];
    const float sgq  = 0.08838834764831845f * gate;
    const float mneg = -1e9f * gate;

    float tv[TK]; int tix[TK];
#pragma unroll
    for (int j = 0; j < TK; ++j) { tv[j] = -3.0e38f; tix[j] = 0; }

    const int koff = l4 * 4;
    __syncthreads();

    for (int ck = 0; ck < 4; ++ck) {
        f32x4 c0 = {0.f, 0.f, 0.f, 0.f};
        f32x4 c1 = {0.f, 0.f, 0.f, 0.f};
        f32x4 c2 = {0.f, 0.f, 0.f, 0.f};
        f32x4 c3 = {0.f, 0.f, 0.f, 0.f};
#pragma unroll
        for (int kb = 0; kb < 4; ++kb) {
            int gq = (kb * 4 + l4);
            short8b bq = *reinterpret_cast<const short8b*>(
                &Qb[qrow * 64 + (((gq) ^ (qrow & 7)) << 2)]);
            int r0 = l15,      p0 = ((gq) ^ (r0 & 7)) << 2;
            int r1 = 16 + l15, p1 = ((gq) ^ (r1 & 7)) << 2;
            int r2 = 32 + l15, p2 = ((gq) ^ (r2 & 7)) << 2;
            int r3 = 48 + l15, p3 = ((gq) ^ (r3 & 7)) << 2;
            short8b a0 = *reinterpret_cast<const short8b*>(&Kb[r0 * 64 + p0]);
            short8b a1 = *reinterpret_cast<const short8b*>(&Kb[r1 * 64 + p1]);
            short8b a2 = *reinterpret_cast<const short8b*>(&Kb[r2 * 64 + p2]);
            short8b a3 = *reinterpret_cast<const short8b*>(&Kb[r3 * 64 + p3]);
            c0 = __builtin_amdgcn_mfma_f32_16x16x32_bf16(a0, bq, c0, 0, 0, 0);
            c1 = __builtin_amdgcn_mfma_f32_16x16x32_bf16(a1, bq, c1, 0, 0, 0);
            c2 = __builtin_amdgcn_mfma_f32_16x16x32_bf16(a2, bq, c2, 0, 0, 0);
            c3 = __builtin_amdgcn_mfma_f32_16x16x32_bf16(a3, bq, c3, 0, 0, 0);
        }

        float4 pf[8];
        if (ck < 3) {
            const float* src = kmat +
                (size_t)(b * TT + sp * 256 + (ck + 1) * 64 + sr) * CQ;
#pragma unroll
            for (int j = 0; j < 4; ++j) {
                int g = sg0 + j * 4;
                pf[j * 2 + 0] = *reinterpret_cast<const float4*>(src + g * 8);
                pf[j * 2 + 1] = *reinterpret_cast<const float4*>(src + g * 8 + 4);
            }
        }

        {
            const int sB = sp * 256 + ck * 64;
            const float* amB = am + b * TT + sB;
            float val;
#define SCAN_TILE(CC, KT)                                                    \
            {                                                                \
                float4 amv = *reinterpret_cast<const float4*>(               \
                    amB + (KT) * 16 + koff);                                 \
                int kbase = sB + (KT) * 16 + koff;                           \
                val = (mq * amv.x == 0.f) ? mneg : CC.x * sgq;               \
                if (val > tv[TK-1]) topk8_insert_strict(tv, tix, val, kbase);\
                val = (mq * amv.y == 0.f) ? mneg : CC.y * sgq;               \
                if (val > tv[TK-1]) topk8_insert_strict(tv, tix, val, kbase+1);\
                val = (mq * amv.z == 0.f) ? mneg : CC.z * sgq;               \
                if (val > tv[TK-1]) topk8_insert_strict(tv, tix, val, kbase+2);\
                val = (mq * amv.w == 0.f) ? mneg : CC.w * sgq;               \
                if (val > tv[TK-1]) topk8_insert_strict(tv, tix, val, kbase+3);\
            }
            SCAN_TILE(c0, 0)
            SCAN_TILE(c1, 1)
            SCAN_TILE(c2, 2)
            SCAN_TILE(c3, 3)
#undef SCAN_TILE
        }
        __syncthreads();

        if (ck < 3) {
#pragma unroll
            for (int j = 0; j < 4; ++j) {
                int g = sg0 + j * 4;
                uint4 u;
                u.x = pack_bf16(pf[j*2].x, pf[j*2].y);
                u.y = pack_bf16(pf[j*2].z, pf[j*2].w);
                u.z = pack_bf16(pf[j*2+1].x, pf[j*2+1].y);
                u.w = pack_bf16(pf[j*2+1].z, pf[j*2+1].w);
                *reinterpret_cast<uint4*>(&Kb[sr * 64 + ((g ^ (sr & 7)) << 2)]) = u;
            }
        }
        __syncthreads();
    }

    // ---- merge the 4 lane-quarters per query (tie-aware) ----
    float* mv = reinterpret_cast<float*>(Qb);
    int*   mi = reinterpret_cast<int*>(Kb);
    int slot = qrow * 4 + l4;
#pragma unroll
    for (int j = 0; j < TK; ++j) { mv[slot * 9 + j] = tv[j]; mi[slot * 9 + j] = tix[j]; }
    __syncthreads();
    if (l4 == 0) {
        for (int u = 1; u < 4; ++u) {
#pragma unroll
            for (int j = 0; j < TK; ++j) {
                float val = mv[(slot + u) * 9 + j];
                int   s   = mi[(slot + u) * 9 + j];
                if (val > tv[TK-1] || (val == tv[TK-1] && s < tix[TK-1]))
                    topk8_insert(tv, tix, val, s);
            }
        }
        int base = (tq * NCH + sp) * TK;
#pragma unroll
        for (int j = 0; j < TK; ++j) pi[base + j] = tix[j];
    }
}

// ---------------------------------------------------------------------------
// K3: fully parallel exact ranking + gather, FUSED (R13 structure). Change
// vs R16: asm keep-alive consuming all 8 loaded vectors BETWEEN the load
// batch and the store batch — forces all 8 global_load_dwordx4 to be
// simultaneously live (8-deep MLP), which the compiler re-serialized in R16
// (VGPR stayed 36). Rule-#17 trick: empty asm with "v" inputs.
// ---------------------------------------------------------------------------
__global__ __launch_bounds__(256) void merge_gather_kernel(
    const float* __restrict__ x,  const float* __restrict__ qm,
    const float* __restrict__ kmat, const float* __restrict__ gates,
    const float* __restrict__ am, const int* __restrict__ pi,
    float* __restrict__ out_g, float* __restrict__ out_i,
    float* __restrict__ out_v)
{
    int t = blockIdx.x;
    int b = t >> 12;
    int tid = threadIdx.x;

    __shared__ float  qrow[CQ];
    __shared__ double svald[NCH * TK];
    __shared__ int    scand[NCH * TK];
    __shared__ int    fidx[TK];

    if (tid < 32) {
        *reinterpret_cast<float4*>(qrow + tid * 4) =
            *reinterpret_cast<const float4*>(qm + (size_t)t * CQ + tid * 4);
    }
    __syncthreads();

    // ---- rescore: c = tid>>1, half = tid&1 handles dims half*64..+63 ----
    {
        int c    = tid >> 1;
        int half = tid & 1;
        int s = pi[(size_t)t * NCH * TK + c];
        const float* kr = kmat + (size_t)(b * TT + s) * CQ + half * 64;
        const float* qh = qrow + half * 64;
        double a0 = 0.0, a1 = 0.0, a2 = 0.0, a3 = 0.0;
#pragma unroll
        for (int d = 0; d < 64; d += 4) {
            float4 kv = *reinterpret_cast<const float4*>(kr + d);
            a0 += (double)qh[d + 0] * (double)kv.x;
            a1 += (double)qh[d + 1] * (double)kv.y;
            a2 += (double)qh[d + 2] * (double)kv.z;
            a3 += (double)qh[d + 3] * (double)kv.w;
        }
        double mine  = (a0 + a1) + (a2 + a3);
        double other = __shfl_xor(mine, 1);
        double lo = half ? other : mine;
        double hi = half ? mine  : other;
        double acc = lo + hi;                       // identical on both lanes
        if (half == 0) {
            float ms  = am[b * TT + s];
            float mqq = am[t];
            double val = (mqq * ms == 0.f) ? -1e9 : acc * 0.08838834764831845;
            val *= (double)gates[t];
            svald[c] = val;
            scand[c] = s;
        }
    }
    __syncthreads();

    // ---- all-pairs rank (parallel top-8; candidates are distinct) ----
    if (tid < NCH * TK) {
        double v = svald[tid]; int si = scand[tid];
        int rank = 0;
        for (int c2 = 0; c2 < NCH * TK; ++c2) {
            double v2 = svald[c2]; int s2 = scand[c2];
            rank += (v2 > v) || (v2 == v && s2 < si);
        }
        if (rank < TK) {
            out_i[t * TK + rank] = (float)si;
            out_v[t * TK + rank] = (float)v;
            fidx[rank] = si;
        }
    }
    __syncthreads();

    // ---- gather: 8 loads forced co-live (asm keep-alive), then 8 stores ----
    {
        f32x4 v0 = *reinterpret_cast<const f32x4*>(
            x + ((size_t)(b * TT + fidx[0])) * DD + tid * 4);
        f32x4 v1 = *reinterpret_cast<const f32x4*>(
            x + ((size_t)(b * TT + fidx[1])) * DD + tid * 4);
        f32x4 v2 = *reinterpret_cast<const f32x4*>(
            x + ((size_t)(b * TT + fidx[2])) * DD + tid * 4);
        f32x4 v3 = *reinterpret_cast<const f32x4*>(
            x + ((size_t)(b * TT + fidx[3])) * DD + tid * 4);
        f32x4 v4 = *reinterpret_cast<const f32x4*>(
            x + ((size_t)(b * TT + fidx[4])) * DD + tid * 4);
        f32x4 v5 = *reinterpret_cast<const f32x4*>(
            x + ((size_t)(b * TT + fidx[5])) * DD + tid * 4);
        f32x4 v6 = *reinterpret_cast<const f32x4*>(
            x + ((size_t)(b * TT + fidx[6])) * DD + tid * 4);
        f32x4 v7 = *reinterpret_cast<const f32x4*>(
            x + ((size_t)(b * TT + fidx[7])) * DD + tid * 4);

        // force all 8 loads resident before any store (compiler cannot
        // re-serialize into load->store pairs: all values consumed here)
        asm volatile("" :: "v"(v0), "v"(v1), "v"(v2), "v"(v3),
                           "v"(v4), "v"(v5), "v"(v6), "v"(v7));

        float* og = out_g + (size_t)t * TK * DD + tid * 4;
        __builtin_nontemporal_store(v0, reinterpret_cast<f32x4*>(og + 0 * DD));
        __builtin_nontemporal_store(v1, reinterpret_cast<f32x4*>(og + 1 * DD));
        __builtin_nontemporal_store(v2, reinterpret_cast<f32x4*>(og + 2 * DD));
        __builtin_nontemporal_store(v3, reinterpret_cast<f32x4*>(og + 3 * DD));
        __builtin_nontemporal_store(v4, reinterpret_cast<f32x4*>(og + 4 * DD));
        __builtin_nontemporal_store(v5, reinterpret_cast<f32x4*>(og + 5 * DD));
        __builtin_nontemporal_store(v6, reinterpret_cast<f32x4*>(og + 6 * DD));
        __builtin_nontemporal_store(v7, reinterpret_cast<f32x4*>(og + 7 * DD));
    }
}

// ---------------------------------------------------------------------------
extern "C" void kernel_launch(void* const* d_in, const int* in_sizes, int n_in,
                              void* d_out, int out_size, void* d_ws, size_t ws_size,
                              hipStream_t stream) {
    const float* x  = (const float*)d_in[0];
    const float* am = (const float*)d_in[1];
    const float* Wq = (const float*)d_in[2];
    const float* bq = (const float*)d_in[3];
    const float* Wk = (const float*)d_in[4];
    const float* bk = (const float*)d_in[5];
    const float* Wg = (const float*)d_in[6];
    const float* bg = (const float*)d_in[7];

    float* ws = (float*)d_ws;
    float* q  = ws;                              // NT*CQ      = 1048576
    float* k  = ws + 1048576;                    // NT*CQ      = 1048576
    float* g  = ws + 2097152;                    // NT         = 8192
    int*   pi = (int*)(ws + 2105344);            // NT*NCH*TK  = 1048576

    float* out_g = (float*)d_out;                // [B,T,K,D] = 67108864
    float* out_i = out_g + 67108864;             // [B,T,K]   = 65536 (as float)
    float* out_v = out_i + 65536;                // [B,T,K]   = 65536

    proj_kernel<<<dim3(NT / 64, 4), 256, 0, stream>>>(x, Wq, bq, Wk, bk, q, k);
    gate_kernel<<<NT / 4, 256, 0, stream>>>(x, Wg, bg, g);
    simtopk_kernel<<<dim3(128, NCH), 256, 0, stream>>>(q, k, g, am, pi);
    merge_gather_kernel<<<NT, 256, 0, stream>>>(x, q, k, g, am, pi,
                                                out_g, out_i, out_v);
}